// Round 26
// baseline (178.768 us; speedup 1.0000x reference)
//
#include <hip/hip_runtime.h>
#include <hip/hip_bf16.h>
#include <cstdint>

typedef __hip_bfloat16 bf16;
typedef __bf16 bf16x8 __attribute__((ext_vector_type(8)));
typedef __bf16 bf16x4 __attribute__((ext_vector_type(4)));
typedef float f32x4 __attribute__((ext_vector_type(4)));
typedef uint32_t u32x4 __attribute__((ext_vector_type(4)));

#define LOG2E 1.4426950408889634f

__device__ __forceinline__ void gload_lds16(const void* g, void* l) {
  __builtin_amdgcn_global_load_lds(
      (const __attribute__((address_space(1))) unsigned int*)g,
      (__attribute__((address_space(3))) unsigned int*)l,
      16, 0, 0);
}

__device__ __forceinline__ uint32_t pack_bf16(float a, float b) {
  const uint32_t ha = (uint32_t)__builtin_bit_cast(uint16_t, (__bf16)a);
  const uint32_t hb = (uint32_t)__builtin_bit_cast(uint16_t, (__bf16)b);
  return ha | (hb << 16);
}

// ---- fused prep (R17-proven): x f32->bf16 convert (blocks 0..2047) +
// 4-matrix transpose+convert (blocks 2048..6143).
__global__ __launch_bounds__(256) void prep(
    const float* __restrict__ x, bf16* __restrict__ xb,
    const float* __restrict__ wq, const float* __restrict__ wk,
    const float* __restrict__ wv, const float* __restrict__ wo,
    bf16* __restrict__ dqkv, bf16* __restrict__ dout) {
  __shared__ float tile[32][33];
  const int bid = blockIdx.x;
  if (bid < 2048) {
    const int i = (bid * 256 + threadIdx.x) * 8;
    const f32x4 a = *(const f32x4*)(x + i);
    const f32x4 b = *(const f32x4*)(x + i + 4);
    bf16x8 o;
#pragma unroll
    for (int j = 0; j < 4; ++j) { o[j] = (__bf16)a[j]; o[4 + j] = (__bf16)b[j]; }
    *(bf16x8*)(xb + i) = o;
    return;
  }
  const int id = bid - 2048;          // 0..4095
  const int z = id >> 10;             // matrix select
  const int t2 = id & 1023;
  const int bx = (t2 & 31) * 32, by = (t2 >> 5) * 32;
  const int tx = threadIdx.x & 31, ty = threadIdx.x >> 5;
  const float* src = (z == 0) ? wq : ((z == 1) ? wk : ((z == 2) ? wv : wo));
  bf16* dst = (z < 3) ? (dqkv + (long)z * 1048576) : dout;
  for (int j = ty; j < 32; j += 8)
    tile[j][tx] = src[(long)(by + j) * 1024 + bx + tx];
  __syncthreads();
  for (int j = ty; j < 32; j += 8)
    dst[(long)(bx + j) * 1024 + by + tx] = __float2bfloat16(tile[tx][j]);
}

// ---- GEMM qkv v4 (R17-proven): 128x96 tiles, 1024 blocks, 4/CU, zero tail ----
__global__ __launch_bounds__(256, 3) void gemm_qkv(
    const bf16* __restrict__ A, const bf16* __restrict__ Bt,
    bf16* __restrict__ Cq, bf16* __restrict__ Ck, bf16* __restrict__ Cv,
    int M, int N, int K) {
  __shared__ __align__(16) bf16 As[128 * 64];
  __shared__ __align__(16) bf16 Bs[96 * 64];

  const int tid = threadIdx.x;
  const int lane = tid & 63;
  const int wave = tid >> 6;
  const int quad = lane >> 4;
  const int l16 = lane & 15;
  const int id = (int)blockIdx.y * 32 + (int)blockIdx.x;
  const int xcd = id & 7, idx = id >> 3;
  const int bxn = xcd * 4 + (idx & 3);
  const int byn = idx >> 2;
  const int m0 = byn * 128;
  const int n0 = bxn * 96;
  const int wm = (wave >> 1) * 64;
  const int wn = (wave & 1) * 48;

  const f32x4 zero4 = {0.f, 0.f, 0.f, 0.f};
  f32x4 acc[4][3];
#pragma unroll
  for (int mi = 0; mi < 4; ++mi)
#pragma unroll
    for (int ni = 0; ni < 3; ++ni) acc[mi][ni] = zero4;

  const int sRow = tid >> 3;
  const int sK = (tid & 7) * 8;
  const int sSwz = sK ^ (8 * (sRow & 7));
  const bf16* Ag = A + (long)(m0 + sRow) * K + sSwz;
  const bf16* Bg = Bt + (long)(n0 + sRow) * K + sSwz;
  const int swzr = 8 * (l16 & 7);

  for (int k0 = 0; k0 < K; k0 += 64) {
#pragma unroll
    for (int j = 0; j < 4; ++j)
      gload_lds16(Ag + k0 + (long)(32 * j) * K, &As[tid * 8 + 2048 * j]);
#pragma unroll
    for (int j = 0; j < 3; ++j)
      gload_lds16(Bg + k0 + (long)(32 * j) * K, &Bs[tid * 8 + 2048 * j]);
    __syncthreads();

#pragma unroll
    for (int ks = 0; ks < 64; ks += 32) {
      const int colr = (ks + quad * 8) ^ swzr;
      bf16x8 af[4], bfv[3];
#pragma unroll
      for (int mi = 0; mi < 4; ++mi)
        af[mi] = *(const bf16x8*)&As[(wm + mi * 16 + l16) * 64 + colr];
#pragma unroll
      for (int ni = 0; ni < 3; ++ni)
        bfv[ni] = *(const bf16x8*)&Bs[(wn + ni * 16 + l16) * 64 + colr];
#pragma unroll
      for (int mi = 0; mi < 4; ++mi)
#pragma unroll
        for (int ni = 0; ni < 3; ++ni)
          acc[mi][ni] = __builtin_amdgcn_mfma_f32_16x16x32_bf16(af[mi], bfv[ni], acc[mi][ni], 0, 0, 0);
    }
    __syncthreads();
  }

#pragma unroll
  for (int mi = 0; mi < 4; ++mi) {
    const int gmb = m0 + wm + mi * 16 + quad * 4;
#pragma unroll
    for (int ni = 0; ni < 3; ++ni) {
      const int n = n0 + wn + ni * 16 + l16;
      const int which = n >> 10, rem = n & 1023;
      const int h = rem >> 6, hd = rem & 63;
      bf16* dst = (which == 0) ? Cq : ((which == 1) ? Ck : Cv);
#pragma unroll
      for (int r = 0; r < 4; ++r) {
        const int gm = gmb + r;
        const int b = gm >> 11, t = gm & 2047;
        dst[(((long)(b * 16 + h)) * 2048 + t) * 64 + hd] = __float2bfloat16(acc[mi][ni][r]);
      }
    }
  }
}

// ---- output GEMM v2 (R13-proven): 64x128 tile, BK=64 + both-sides XOR swizzle ----
__global__ __launch_bounds__(256, 3) void gemm_out(
    const bf16* __restrict__ A, const bf16* __restrict__ Bt,
    const float* __restrict__ bias, float* __restrict__ Cout,
    int M, int N, int K) {
  __shared__ __align__(16) bf16 As[64 * 64];
  __shared__ __align__(16) bf16 Bs[128 * 64];

  const int tid = threadIdx.x;
  const int lane = tid & 63;
  const int wave = tid >> 6;
  const int quad = lane >> 4;
  const int l16 = lane & 15;
  const int id = (int)blockIdx.y * 8 + (int)blockIdx.x;
  const int m0 = (id >> 3) * 64;
  const int n0 = (id & 7) * 128;
  const int wm = (wave & 1) * 32;
  const int wn = (wave >> 1) * 64;

  const f32x4 zero4 = {0.f, 0.f, 0.f, 0.f};
  f32x4 acc[2][4];
#pragma unroll
  for (int mi = 0; mi < 2; ++mi)
#pragma unroll
    for (int ni = 0; ni < 4; ++ni) acc[mi][ni] = zero4;

  const int sRow = tid >> 3;
  const int sK = (tid & 7) * 8;
  const int sSwz = sK ^ (8 * (sRow & 7));
  const bf16* Ag = A + (long)(m0 + sRow) * K + sSwz;
  const bf16* Bg = Bt + (long)(n0 + sRow) * K + sSwz;
  const int swzr = 8 * (l16 & 7);

  for (int k0 = 0; k0 < K; k0 += 64) {
#pragma unroll
    for (int j = 0; j < 2; ++j)
      gload_lds16(Ag + k0 + (long)(32 * j) * K, &As[tid * 8 + 2048 * j]);
#pragma unroll
    for (int j = 0; j < 4; ++j)
      gload_lds16(Bg + k0 + (long)(32 * j) * K, &Bs[tid * 8 + 2048 * j]);
    __syncthreads();

#pragma unroll
    for (int ks = 0; ks < 64; ks += 32) {
      const int colr = (ks + quad * 8) ^ swzr;
      bf16x8 af[2], bfv[4];
#pragma unroll
      for (int mi = 0; mi < 2; ++mi)
        af[mi] = *(const bf16x8*)&As[(wm + mi * 16 + l16) * 64 + colr];
#pragma unroll
      for (int ni = 0; ni < 4; ++ni)
        bfv[ni] = *(const bf16x8*)&Bs[(wn + ni * 16 + l16) * 64 + colr];
#pragma unroll
      for (int mi = 0; mi < 2; ++mi)
#pragma unroll
        for (int ni = 0; ni < 4; ++ni)
          acc[mi][ni] = __builtin_amdgcn_mfma_f32_16x16x32_bf16(af[mi], bfv[ni], acc[mi][ni], 0, 0, 0);
    }
    __syncthreads();
  }

#pragma unroll
  for (int mi = 0; mi < 2; ++mi) {
    const int gmb = m0 + wm + mi * 16 + quad * 4;
#pragma unroll
    for (int ni = 0; ni < 4; ++ni) {
      const int n = n0 + wn + ni * 16 + l16;
      const float bv = bias[n];
#pragma unroll
      for (int r = 0; r < 4; ++r)
        Cout[(long)(gmb + r) * N + n] = acc[mi][ni][r] + bv;
    }
  }
}

// ---- flash attention v12b (R18/R20-proven): uniform-length blocks + deferred
// l-reduce. Single-buffer LDS, 2 barriers/iter; qt pairing {p, 31-p} ->
// every block 17-18 iters, zero drain; XCD-local bh remap, static-shift
// softmax, permuted Vt, zero-select exchange, register K/V prefetch.
// Ledger: dbuf (R10), k-split (R12/R14), gload_lds-K + peeled tail (R19)
// all regressed -> v12 structure is the local optimum at this design point.
// grid (16, 32); block 256 (4 waves x 16 q-rows)
__global__ __launch_bounds__(256, 3) void attn_kernel(
    const bf16* __restrict__ Q, const bf16* __restrict__ Kg, const bf16* __restrict__ Vg,
    bf16* __restrict__ ctx) {
  constexpr int KSTR = 72, VSTR = 136;
  __shared__ __align__(16) bf16 Ks[128 * KSTR];     // [t][d]
  __shared__ __align__(16) bf16 Vt[64 * VSTR];      // [d][c(k)]

  const int tid = threadIdx.x;
  const int lane = tid & 63;
  const int wave = tid >> 6;
  const int quad = lane >> 4;
  const int l16 = lane & 15;

  const int id = (int)blockIdx.y * 16 + (int)blockIdx.x;
  const int g = id & 7;
  const int bh = g * 4 + ((id >> 3) & 3);
  const int p = id >> 5;

  const long base = (long)bh * 2048 * 64;
  const int b = bh >> 4, h = bh & 15;

  const int krow = tid >> 1;
  const int kc32 = (tid & 1) * 32;
  const int vr4 = (tid & 31) * 4;
  const int vd8 = (tid >> 5) * 8;
  const int vb4 = (vr4 >> 4) & 1;
  const int vc4 = (vr4 & ~31) + 8 * (((vr4 >> 2) & 3) ^ vb4) + 4 * vb4;

  const float negsh = -12.0f * LOG2E;
  const f32x4 zero4 = {0.f, 0.f, 0.f, 0.f};

#pragma unroll 1
  for (int seg = 0; seg < 2; ++seg) {
    const int qt = seg ? (31 - p) : p;
    const int qbase = qt * 64 + wave * 16;
    const int q = qbase + l16;

    bf16x8 qf0 = *(const bf16x8*)(Q + base + (long)(qbase + l16) * 64 + quad * 8);
    bf16x8 qf1 = *(const bf16x8*)(Q + base + (long)(qbase + l16) * 64 + 32 + quad * 8);
#pragma unroll
    for (int j = 0; j < 8; ++j) {
      qf0[j] = (__bf16)((float)qf0[j] * 0.125f);
      qf1[j] = (__bf16)((float)qf1[j] * 0.125f);
    }

    float l_part = 0.f;  // per-lane partial; cross-quad reduce deferred
    f32x4 oacc[4];
#pragma unroll
    for (int nb = 0; nb < 4; ++nb) oacc[nb] = zero4;

    const int nk = (qt + 2) >> 1;
    bf16x8 kr[4], vv[4];
    {
      const bf16* kp = Kg + base + (long)krow * 64 + kc32;
#pragma unroll
      for (int i = 0; i < 4; ++i) kr[i] = *(const bf16x8*)(kp + i * 8);
#pragma unroll
      for (int i = 0; i < 4; ++i)
        vv[i] = *(const bf16x8*)(Vg + base + (long)(vr4 + i) * 64 + vd8);
    }

    for (int kt = 0; kt < nk; ++kt) {
      const int k0 = kt * 128;
#pragma unroll
      for (int i = 0; i < 4; ++i)
        *(bf16x8*)&Ks[krow * KSTR + kc32 + i * 8] = kr[i];
#pragma unroll
      for (int j = 0; j < 8; ++j) {
        bf16x4 t;
        t[0] = vv[0][j]; t[1] = vv[1][j]; t[2] = vv[2][j]; t[3] = vv[3][j];
        *(bf16x4*)&Vt[(vd8 + j) * VSTR + vc4] = t;
      }
      __syncthreads();
      if (kt + 1 < nk) {
        const bf16* kp = Kg + base + (long)(k0 + 128 + krow) * 64 + kc32;
#pragma unroll
        for (int i = 0; i < 4; ++i) kr[i] = *(const bf16x8*)(kp + i * 8);
#pragma unroll
        for (int i = 0; i < 4; ++i)
          vv[i] = *(const bf16x8*)(Vg + base + (long)(k0 + 128 + vr4 + i) * 64 + vd8);
      }

      f32x4 s8[8];
      __builtin_amdgcn_s_setprio(1);
#pragma unroll
      for (int kb = 0; kb < 8; ++kb) {
        const bf16x8 kb0 = *(const bf16x8*)&Ks[(kb * 16 + l16) * KSTR + quad * 8];
        const bf16x8 kb1 = *(const bf16x8*)&Ks[(kb * 16 + l16) * KSTR + 32 + quad * 8];
        f32x4 a = zero4;
        a = __builtin_amdgcn_mfma_f32_16x16x32_bf16(kb0, qf0, a, 0, 0, 0);
        a = __builtin_amdgcn_mfma_f32_16x16x32_bf16(kb1, qf1, a, 0, 0, 0);
        s8[kb] = a;
      }
      __builtin_amdgcn_s_setprio(0);

      if (kt == nk - 1) {
        const int qg = q - k0 - quad * 4;
#pragma unroll
        for (int kb = 0; kb < 8; ++kb)
#pragma unroll
          for (int r = 0; r < 4; ++r)
            s8[kb][r] = (kb * 16 + r <= qg) ? s8[kb][r] : -1e30f;
      }

      float rsum = 0.f;
      u32x4 paw[4];
#pragma unroll
      for (int kk = 0; kk < 4; ++kk) {
        const float p0 = exp2f(fmaf(s8[2 * kk][0], LOG2E, negsh));
        const float p1 = exp2f(fmaf(s8[2 * kk][1], LOG2E, negsh));
        const float p2 = exp2f(fmaf(s8[2 * kk][2], LOG2E, negsh));
        const float p3 = exp2f(fmaf(s8[2 * kk][3], LOG2E, negsh));
        const float p4 = exp2f(fmaf(s8[2 * kk + 1][0], LOG2E, negsh));
        const float p5 = exp2f(fmaf(s8[2 * kk + 1][1], LOG2E, negsh));
        const float p6 = exp2f(fmaf(s8[2 * kk + 1][2], LOG2E, negsh));
        const float p7 = exp2f(fmaf(s8[2 * kk + 1][3], LOG2E, negsh));
        rsum += ((p0 + p1) + (p2 + p3)) + ((p4 + p5) + (p6 + p7));
        u32x4 w;
        w[0] = pack_bf16(p0, p1);
        w[1] = pack_bf16(p2, p3);
        w[2] = (uint32_t)__shfl_xor((int)pack_bf16(p4, p5), 16);
        w[3] = (uint32_t)__shfl_xor((int)pack_bf16(p6, p7), 16);
        paw[kk] = w;
      }
      l_part += rsum;

      __builtin_amdgcn_s_setprio(1);
#pragma unroll
      for (int kk = 0; kk < 4; ++kk) {
        const bf16x8 pa = __builtin_bit_cast(bf16x8, paw[kk]);
#pragma unroll
        for (int nb2 = 0; nb2 < 4; ++nb2) {
          const bf16x8 vb = *(const bf16x8*)&Vt[(nb2 * 16 + l16) * VSTR + kk * 32 + quad * 8];
          oacc[nb2] = __builtin_amdgcn_mfma_f32_16x16x32_bf16(pa, vb, oacc[nb2], 0, 0, 0);
        }
      }
      __builtin_amdgcn_s_setprio(0);
      __syncthreads();
    }

    // single cross-quad l-reduce per segment (deferred)
    float l_i = l_part;
    l_i += __shfl_xor(l_i, 16);
    l_i += __shfl_xor(l_i, 32);

    float linv[4];
#pragma unroll
    for (int r = 0; r < 4; ++r) linv[r] = 1.0f / __shfl(l_i, quad * 4 + r);
#pragma unroll
    for (int r = 0; r < 4; ++r) {
      const int t = qbase + quad * 4 + r;
#pragma unroll
      for (int nb2 = 0; nb2 < 4; ++nb2) {
        const int d = h * 64 + nb2 * 16 + l16;
        ctx[((long)b * 2048 + t) * 1024 + d] = __float2bfloat16(oacc[nb2][r] * linv[r]);
      }
    }
  }
}

extern "C" void kernel_launch(void* const* d_in, const int* in_sizes, int n_in,
                              void* d_out, int out_size, void* d_ws, size_t ws_size,
                              hipStream_t stream) {
  const float* x  = (const float*)d_in[0];
  const float* wq = (const float*)d_in[1];
  const float* wk = (const float*)d_in[2];
  const float* wv = (const float*)d_in[3];
  const float* wo = (const float*)d_in[4];
  const float* bo = (const float*)d_in[5];
  float* out = (float*)d_out;

  bf16* Wtqkv = (bf16*)d_ws;            // 3 * 1048576
  bf16* Wto   = Wtqkv + 3145728;        // 1048576
  bf16* xb    = Wto + 1048576;          // 4194304 (reused as Cx)
  bf16* Qb    = xb + 4194304;
  bf16* Kb    = Qb + 4194304;
  bf16* Vb    = Kb + 4194304;
  bf16* Cx    = xb;

  hipLaunchKernelGGL(prep, dim3(6144), dim3(256), 0, stream,
                     x, xb, wq, wk, wv, wo, Wtqkv, Wto);

  hipLaunchKernelGGL(gemm_qkv, dim3(32, 32), dim3(256), 0, stream,
                     xb, Wtqkv, Qb, Kb, Vb, 4096, 3072, 1024);

  hipLaunchKernelGGL(attn_kernel, dim3(16, 32), dim3(256), 0, stream, Qb, Kb, Vb, Cx);

  hipLaunchKernelGGL(gemm_out, dim3(8, 64), dim3(256), 0, stream,
                     Cx, Wto, bo, out, 4096, 1024, 1024);
}

// Round 27
// 175.995 us; speedup vs baseline: 1.0158x; 1.0158x over previous
//
#include <hip/hip_runtime.h>
#include <hip/hip_bf16.h>
#include <cstdint>

typedef __hip_bfloat16 bf16;
typedef __bf16 bf16x8 __attribute__((ext_vector_type(8)));
typedef __bf16 bf16x4 __attribute__((ext_vector_type(4)));
typedef float f32x4 __attribute__((ext_vector_type(4)));
typedef uint32_t u32x4 __attribute__((ext_vector_type(4)));

#define LOG2E 1.4426950408889634f

__device__ __forceinline__ void gload_lds16(const void* g, void* l) {
  __builtin_amdgcn_global_load_lds(
      (const __attribute__((address_space(1))) unsigned int*)g,
      (__attribute__((address_space(3))) unsigned int*)l,
      16, 0, 0);
}

__device__ __forceinline__ uint32_t pack_bf16(float a, float b) {
  const uint32_t ha = (uint32_t)__builtin_bit_cast(uint16_t, (__bf16)a);
  const uint32_t hb = (uint32_t)__builtin_bit_cast(uint16_t, (__bf16)b);
  return ha | (hb << 16);
}

// ---- fused prep (R17-proven): x f32->bf16 convert (blocks 0..2047) +
// 4-matrix transpose+convert (blocks 2048..6143).
__global__ __launch_bounds__(256) void prep(
    const float* __restrict__ x, bf16* __restrict__ xb,
    const float* __restrict__ wq, const float* __restrict__ wk,
    const float* __restrict__ wv, const float* __restrict__ wo,
    bf16* __restrict__ dqkv, bf16* __restrict__ dout) {
  __shared__ float tile[32][33];
  const int bid = blockIdx.x;
  if (bid < 2048) {
    const int i = (bid * 256 + threadIdx.x) * 8;
    const f32x4 a = *(const f32x4*)(x + i);
    const f32x4 b = *(const f32x4*)(x + i + 4);
    bf16x8 o;
#pragma unroll
    for (int j = 0; j < 4; ++j) { o[j] = (__bf16)a[j]; o[4 + j] = (__bf16)b[j]; }
    *(bf16x8*)(xb + i) = o;
    return;
  }
  const int id = bid - 2048;          // 0..4095
  const int z = id >> 10;             // matrix select
  const int t2 = id & 1023;
  const int bx = (t2 & 31) * 32, by = (t2 >> 5) * 32;
  const int tx = threadIdx.x & 31, ty = threadIdx.x >> 5;
  const float* src = (z == 0) ? wq : ((z == 1) ? wk : ((z == 2) ? wv : wo));
  bf16* dst = (z < 3) ? (dqkv + (long)z * 1048576) : dout;
  for (int j = ty; j < 32; j += 8)
    tile[j][tx] = src[(long)(by + j) * 1024 + bx + tx];
  __syncthreads();
  for (int j = ty; j < 32; j += 8)
    dst[(long)(bx + j) * 1024 + by + tx] = __float2bfloat16(tile[tx][j]);
}

// ---- GEMM qkv v4 (R17-proven): 128x96 tiles, 1024 blocks, 4/CU, zero tail ----
__global__ __launch_bounds__(256, 3) void gemm_qkv(
    const bf16* __restrict__ A, const bf16* __restrict__ Bt,
    bf16* __restrict__ Cq, bf16* __restrict__ Ck, bf16* __restrict__ Cv,
    int M, int N, int K) {
  __shared__ __align__(16) bf16 As[128 * 64];
  __shared__ __align__(16) bf16 Bs[96 * 64];

  const int tid = threadIdx.x;
  const int lane = tid & 63;
  const int wave = tid >> 6;
  const int quad = lane >> 4;
  const int l16 = lane & 15;
  const int id = (int)blockIdx.y * 32 + (int)blockIdx.x;
  const int xcd = id & 7, idx = id >> 3;
  const int bxn = xcd * 4 + (idx & 3);
  const int byn = idx >> 2;
  const int m0 = byn * 128;
  const int n0 = bxn * 96;
  const int wm = (wave >> 1) * 64;
  const int wn = (wave & 1) * 48;

  const f32x4 zero4 = {0.f, 0.f, 0.f, 0.f};
  f32x4 acc[4][3];
#pragma unroll
  for (int mi = 0; mi < 4; ++mi)
#pragma unroll
    for (int ni = 0; ni < 3; ++ni) acc[mi][ni] = zero4;

  const int sRow = tid >> 3;
  const int sK = (tid & 7) * 8;
  const int sSwz = sK ^ (8 * (sRow & 7));
  const bf16* Ag = A + (long)(m0 + sRow) * K + sSwz;
  const bf16* Bg = Bt + (long)(n0 + sRow) * K + sSwz;
  const int swzr = 8 * (l16 & 7);

  for (int k0 = 0; k0 < K; k0 += 64) {
#pragma unroll
    for (int j = 0; j < 4; ++j)
      gload_lds16(Ag + k0 + (long)(32 * j) * K, &As[tid * 8 + 2048 * j]);
#pragma unroll
    for (int j = 0; j < 3; ++j)
      gload_lds16(Bg + k0 + (long)(32 * j) * K, &Bs[tid * 8 + 2048 * j]);
    __syncthreads();

#pragma unroll
    for (int ks = 0; ks < 64; ks += 32) {
      const int colr = (ks + quad * 8) ^ swzr;
      bf16x8 af[4], bfv[3];
#pragma unroll
      for (int mi = 0; mi < 4; ++mi)
        af[mi] = *(const bf16x8*)&As[(wm + mi * 16 + l16) * 64 + colr];
#pragma unroll
      for (int ni = 0; ni < 3; ++ni)
        bfv[ni] = *(const bf16x8*)&Bs[(wn + ni * 16 + l16) * 64 + colr];
#pragma unroll
      for (int mi = 0; mi < 4; ++mi)
#pragma unroll
        for (int ni = 0; ni < 3; ++ni)
          acc[mi][ni] = __builtin_amdgcn_mfma_f32_16x16x32_bf16(af[mi], bfv[ni], acc[mi][ni], 0, 0, 0);
    }
    __syncthreads();
  }

#pragma unroll
  for (int mi = 0; mi < 4; ++mi) {
    const int gmb = m0 + wm + mi * 16 + quad * 4;
#pragma unroll
    for (int ni = 0; ni < 3; ++ni) {
      const int n = n0 + wn + ni * 16 + l16;
      const int which = n >> 10, rem = n & 1023;
      const int h = rem >> 6, hd = rem & 63;
      bf16* dst = (which == 0) ? Cq : ((which == 1) ? Ck : Cv);
#pragma unroll
      for (int r = 0; r < 4; ++r) {
        const int gm = gmb + r;
        const int b = gm >> 11, t = gm & 2047;
        dst[(((long)(b * 16 + h)) * 2048 + t) * 64 + hd] = __float2bfloat16(acc[mi][ni][r]);
      }
    }
  }
}

// ---- output GEMM v2 (R13-proven): 64x128 tile, BK=64 + both-sides XOR swizzle ----
__global__ __launch_bounds__(256, 3) void gemm_out(
    const bf16* __restrict__ A, const bf16* __restrict__ Bt,
    const float* __restrict__ bias, float* __restrict__ Cout,
    int M, int N, int K) {
  __shared__ __align__(16) bf16 As[64 * 64];
  __shared__ __align__(16) bf16 Bs[128 * 64];

  const int tid = threadIdx.x;
  const int lane = tid & 63;
  const int wave = tid >> 6;
  const int quad = lane >> 4;
  const int l16 = lane & 15;
  const int id = (int)blockIdx.y * 8 + (int)blockIdx.x;
  const int m0 = (id >> 3) * 64;
  const int n0 = (id & 7) * 128;
  const int wm = (wave & 1) * 32;
  const int wn = (wave >> 1) * 64;

  const f32x4 zero4 = {0.f, 0.f, 0.f, 0.f};
  f32x4 acc[2][4];
#pragma unroll
  for (int mi = 0; mi < 2; ++mi)
#pragma unroll
    for (int ni = 0; ni < 4; ++ni) acc[mi][ni] = zero4;

  const int sRow = tid >> 3;
  const int sK = (tid & 7) * 8;
  const int sSwz = sK ^ (8 * (sRow & 7));
  const bf16* Ag = A + (long)(m0 + sRow) * K + sSwz;
  const bf16* Bg = Bt + (long)(n0 + sRow) * K + sSwz;
  const int swzr = 8 * (l16 & 7);

  for (int k0 = 0; k0 < K; k0 += 64) {
#pragma unroll
    for (int j = 0; j < 2; ++j)
      gload_lds16(Ag + k0 + (long)(32 * j) * K, &As[tid * 8 + 2048 * j]);
#pragma unroll
    for (int j = 0; j < 4; ++j)
      gload_lds16(Bg + k0 + (long)(32 * j) * K, &Bs[tid * 8 + 2048 * j]);
    __syncthreads();

#pragma unroll
    for (int ks = 0; ks < 64; ks += 32) {
      const int colr = (ks + quad * 8) ^ swzr;
      bf16x8 af[2], bfv[4];
#pragma unroll
      for (int mi = 0; mi < 2; ++mi)
        af[mi] = *(const bf16x8*)&As[(wm + mi * 16 + l16) * 64 + colr];
#pragma unroll
      for (int ni = 0; ni < 4; ++ni)
        bfv[ni] = *(const bf16x8*)&Bs[(wn + ni * 16 + l16) * 64 + colr];
#pragma unroll
      for (int mi = 0; mi < 2; ++mi)
#pragma unroll
        for (int ni = 0; ni < 4; ++ni)
          acc[mi][ni] = __builtin_amdgcn_mfma_f32_16x16x32_bf16(af[mi], bfv[ni], acc[mi][ni], 0, 0, 0);
    }
    __syncthreads();
  }

#pragma unroll
  for (int mi = 0; mi < 2; ++mi) {
    const int gmb = m0 + wm + mi * 16 + quad * 4;
#pragma unroll
    for (int ni = 0; ni < 4; ++ni) {
      const int n = n0 + wn + ni * 16 + l16;
      const float bv = bias[n];
#pragma unroll
      for (int r = 0; r < 4; ++r)
        Cout[(long)(gmb + r) * N + n] = acc[mi][ni][r] + bv;
    }
  }
}

// ---- flash attention v12b (R18/R20-proven): uniform-length blocks + deferred
// l-reduce. Single-buffer LDS, 2 barriers/iter; qt pairing {p, 31-p} ->
// every block 17-18 iters, zero drain; XCD-local bh remap, static-shift
// softmax, permuted Vt, zero-select exchange, register K/V prefetch.
// Ledger: dbuf (R10), k-split (R12/R14), gload_lds-K + peeled tail (R19)
// all regressed -> v12 structure is the local optimum at this design point.
// grid (16, 32); block 256 (4 waves x 16 q-rows)
__global__ __launch_bounds__(256, 3) void attn_kernel(
    const bf16* __restrict__ Q, const bf16* __restrict__ Kg, const bf16* __restrict__ Vg,
    bf16* __restrict__ ctx) {
  constexpr int KSTR = 72, VSTR = 136;
  __shared__ __align__(16) bf16 Ks[128 * KSTR];     // [t][d]
  __shared__ __align__(16) bf16 Vt[64 * VSTR];      // [d][c(k)]

  const int tid = threadIdx.x;
  const int lane = tid & 63;
  const int wave = tid >> 6;
  const int quad = lane >> 4;
  const int l16 = lane & 15;

  const int id = (int)blockIdx.y * 16 + (int)blockIdx.x;
  const int g = id & 7;
  const int bh = g * 4 + ((id >> 3) & 3);
  const int p = id >> 5;

  const long base = (long)bh * 2048 * 64;
  const int b = bh >> 4, h = bh & 15;

  const int krow = tid >> 1;
  const int kc32 = (tid & 1) * 32;
  const int vr4 = (tid & 31) * 4;
  const int vd8 = (tid >> 5) * 8;
  const int vb4 = (vr4 >> 4) & 1;
  const int vc4 = (vr4 & ~31) + 8 * (((vr4 >> 2) & 3) ^ vb4) + 4 * vb4;

  const float negsh = -12.0f * LOG2E;
  const f32x4 zero4 = {0.f, 0.f, 0.f, 0.f};

#pragma unroll 1
  for (int seg = 0; seg < 2; ++seg) {
    const int qt = seg ? (31 - p) : p;
    const int qbase = qt * 64 + wave * 16;
    const int q = qbase + l16;

    bf16x8 qf0 = *(const bf16x8*)(Q + base + (long)(qbase + l16) * 64 + quad * 8);
    bf16x8 qf1 = *(const bf16x8*)(Q + base + (long)(qbase + l16) * 64 + 32 + quad * 8);
#pragma unroll
    for (int j = 0; j < 8; ++j) {
      qf0[j] = (__bf16)((float)qf0[j] * 0.125f);
      qf1[j] = (__bf16)((float)qf1[j] * 0.125f);
    }

    float l_part = 0.f;  // per-lane partial; cross-quad reduce deferred
    f32x4 oacc[4];
#pragma unroll
    for (int nb = 0; nb < 4; ++nb) oacc[nb] = zero4;

    const int nk = (qt + 2) >> 1;
    bf16x8 kr[4], vv[4];
    {
      const bf16* kp = Kg + base + (long)krow * 64 + kc32;
#pragma unroll
      for (int i = 0; i < 4; ++i) kr[i] = *(const bf16x8*)(kp + i * 8);
#pragma unroll
      for (int i = 0; i < 4; ++i)
        vv[i] = *(const bf16x8*)(Vg + base + (long)(vr4 + i) * 64 + vd8);
    }

    for (int kt = 0; kt < nk; ++kt) {
      const int k0 = kt * 128;
#pragma unroll
      for (int i = 0; i < 4; ++i)
        *(bf16x8*)&Ks[krow * KSTR + kc32 + i * 8] = kr[i];
#pragma unroll
      for (int j = 0; j < 8; ++j) {
        bf16x4 t;
        t[0] = vv[0][j]; t[1] = vv[1][j]; t[2] = vv[2][j]; t[3] = vv[3][j];
        *(bf16x4*)&Vt[(vd8 + j) * VSTR + vc4] = t;
      }
      __syncthreads();
      if (kt + 1 < nk) {
        const bf16* kp = Kg + base + (long)(k0 + 128 + krow) * 64 + kc32;
#pragma unroll
        for (int i = 0; i < 4; ++i) kr[i] = *(const bf16x8*)(kp + i * 8);
#pragma unroll
        for (int i = 0; i < 4; ++i)
          vv[i] = *(const bf16x8*)(Vg + base + (long)(k0 + 128 + vr4 + i) * 64 + vd8);
      }

      f32x4 s8[8];
      __builtin_amdgcn_s_setprio(1);
#pragma unroll
      for (int kb = 0; kb < 8; ++kb) {
        const bf16x8 kb0 = *(const bf16x8*)&Ks[(kb * 16 + l16) * KSTR + quad * 8];
        const bf16x8 kb1 = *(const bf16x8*)&Ks[(kb * 16 + l16) * KSTR + 32 + quad * 8];
        f32x4 a = zero4;
        a = __builtin_amdgcn_mfma_f32_16x16x32_bf16(kb0, qf0, a, 0, 0, 0);
        a = __builtin_amdgcn_mfma_f32_16x16x32_bf16(kb1, qf1, a, 0, 0, 0);
        s8[kb] = a;
      }
      __builtin_amdgcn_s_setprio(0);

      if (kt == nk - 1) {
        const int qg = q - k0 - quad * 4;
#pragma unroll
        for (int kb = 0; kb < 8; ++kb)
#pragma unroll
          for (int r = 0; r < 4; ++r)
            s8[kb][r] = (kb * 16 + r <= qg) ? s8[kb][r] : -1e30f;
      }

      float rsum = 0.f;
      u32x4 paw[4];
#pragma unroll
      for (int kk = 0; kk < 4; ++kk) {
        const float p0 = exp2f(fmaf(s8[2 * kk][0], LOG2E, negsh));
        const float p1 = exp2f(fmaf(s8[2 * kk][1], LOG2E, negsh));
        const float p2 = exp2f(fmaf(s8[2 * kk][2], LOG2E, negsh));
        const float p3 = exp2f(fmaf(s8[2 * kk][3], LOG2E, negsh));
        const float p4 = exp2f(fmaf(s8[2 * kk + 1][0], LOG2E, negsh));
        const float p5 = exp2f(fmaf(s8[2 * kk + 1][1], LOG2E, negsh));
        const float p6 = exp2f(fmaf(s8[2 * kk + 1][2], LOG2E, negsh));
        const float p7 = exp2f(fmaf(s8[2 * kk + 1][3], LOG2E, negsh));
        rsum += ((p0 + p1) + (p2 + p3)) + ((p4 + p5) + (p6 + p7));
        u32x4 w;
        w[0] = pack_bf16(p0, p1);
        w[1] = pack_bf16(p2, p3);
        w[2] = (uint32_t)__shfl_xor((int)pack_bf16(p4, p5), 16);
        w[3] = (uint32_t)__shfl_xor((int)pack_bf16(p6, p7), 16);
        paw[kk] = w;
      }
      l_part += rsum;

      __builtin_amdgcn_s_setprio(1);
#pragma unroll
      for (int kk = 0; kk < 4; ++kk) {
        const bf16x8 pa = __builtin_bit_cast(bf16x8, paw[kk]);
#pragma unroll
        for (int nb2 = 0; nb2 < 4; ++nb2) {
          const bf16x8 vb = *(const bf16x8*)&Vt[(nb2 * 16 + l16) * VSTR + kk * 32 + quad * 8];
          oacc[nb2] = __builtin_amdgcn_mfma_f32_16x16x32_bf16(pa, vb, oacc[nb2], 0, 0, 0);
        }
      }
      __builtin_amdgcn_s_setprio(0);
      __syncthreads();
    }

    // single cross-quad l-reduce per segment (deferred)
    float l_i = l_part;
    l_i += __shfl_xor(l_i, 16);
    l_i += __shfl_xor(l_i, 32);

    float linv[4];
#pragma unroll
    for (int r = 0; r < 4; ++r) linv[r] = 1.0f / __shfl(l_i, quad * 4 + r);
#pragma unroll
    for (int r = 0; r < 4; ++r) {
      const int t = qbase + quad * 4 + r;
#pragma unroll
      for (int nb2 = 0; nb2 < 4; ++nb2) {
        const int d = h * 64 + nb2 * 16 + l16;
        ctx[((long)b * 2048 + t) * 1024 + d] = __float2bfloat16(oacc[nb2][r] * linv[r]);
      }
    }
  }
}

extern "C" void kernel_launch(void* const* d_in, const int* in_sizes, int n_in,
                              void* d_out, int out_size, void* d_ws, size_t ws_size,
                              hipStream_t stream) {
  const float* x  = (const float*)d_in[0];
  const float* wq = (const float*)d_in[1];
  const float* wk = (const float*)d_in[2];
  const float* wv = (const float*)d_in[3];
  const float* wo = (const float*)d_in[4];
  const float* bo = (const float*)d_in[5];
  float* out = (float*)d_out;

  bf16* Wtqkv = (bf16*)d_ws;            // 3 * 1048576
  bf16* Wto   = Wtqkv + 3145728;        // 1048576
  bf16* xb    = Wto + 1048576;          // 4194304 (reused as Cx)
  bf16* Qb    = xb + 4194304;
  bf16* Kb    = Qb + 4194304;
  bf16* Vb    = Kb + 4194304;
  bf16* Cx    = xb;

  hipLaunchKernelGGL(prep, dim3(6144), dim3(256), 0, stream,
                     x, xb, wq, wk, wv, wo, Wtqkv, Wto);

  hipLaunchKernelGGL(gemm_qkv, dim3(32, 32), dim3(256), 0, stream,
                     xb, Wtqkv, Qb, Kb, Vb, 4096, 3072, 1024);

  hipLaunchKernelGGL(attn_kernel, dim3(16, 32), dim3(256), 0, stream, Qb, Kb, Vb, Cx);

  hipLaunchKernelGGL(gemm_out, dim3(8, 64), dim3(256), 0, stream,
                     Cx, Wto, bo, out, 4096, 1024, 1024);
}